// Round 11
// baseline (94.106 us; speedup 1.0000x reference)
//
#include <hip/hip_runtime.h>
#include <hip/hip_bf16.h>

// ComputeEmbeddings: out[b,s,d] = embed_weight[inputs[b,s], d] + PE[s,d]
//   B=32, S=5000, D=512, VOCAB=32000, fp32. absmax threshold 0.128.
//
// R10 -> R11: PURE A/B — identical to R10 except output stores are regular
// (non-nontemporal). R10 changed two variables at once (XCD dim-slicing +
// nt stores); this round isolates nt's contribution.
//   H1: nt protects the 2.05MB L2-resident qtab slice from the 41MB/XCD
//       write sweep -> removing it regresses (87-92us). Keep R10.
//   H2: nt 16B stores in scattered 256B chunks lose write efficiency ->
//       removing it improves (73-78us).
//   Neutral: drop nt, declare near-floor.

#define EMB_B  32
#define EMB_S  5000
#define EMB_D  512
#define VOCAB  32000
#define NPOS   (EMB_B * EMB_S)        // 160000
#define NSLICE 8
#define SLICE_BYTES ((size_t)VOCAB * 64)   // 2,048,000 B per slice

typedef float f32x4 __attribute__((ext_vector_type(4)));

#define LOG2_10000 13.287712379549449f
#define FREQ_C (-(LOG2_10000 / 256.0f))   // inv_freq(i) = exp2(i * FREQ_C)

// ---------- phase 1: per-row int8 quantization into SLICED layout ----------
__global__ __launch_bounds__(256) void quant_kernel(
    const float* __restrict__ weight,   // [VOCAB, 512]
    signed char* __restrict__ qtab,     // [8][VOCAB, 64]
    float* __restrict__ scales)         // [VOCAB]
{
    const int gtid = blockIdx.x * 256 + threadIdx.x;
    const int row  = gtid >> 6;          // one wave per row
    const int lane = gtid & 63;
    if (row >= VOCAB) return;

    const f32x4* __restrict__ w4 =
        reinterpret_cast<const f32x4*>(weight + (size_t)row * EMB_D);
    const f32x4 a = w4[lane * 2];
    const f32x4 b = w4[lane * 2 + 1];

    float m = fmaxf(fmaxf(fabsf(a.x), fabsf(a.y)), fmaxf(fabsf(a.z), fabsf(a.w)));
    m = fmaxf(m, fmaxf(fmaxf(fabsf(b.x), fabsf(b.y)), fmaxf(fabsf(b.z), fabsf(b.w))));
    #pragma unroll
    for (int off = 1; off < 64; off <<= 1)
        m = fmaxf(m, __shfl_xor(m, off));

    const float scale = m * (1.0f / 127.0f);
    const float inv   = (m > 0.0f) ? (127.0f / m) : 0.0f;

    signed char q[8];
    q[0] = (signed char)__float2int_rn(a.x * inv);
    q[1] = (signed char)__float2int_rn(a.y * inv);
    q[2] = (signed char)__float2int_rn(a.z * inv);
    q[3] = (signed char)__float2int_rn(a.w * inv);
    q[4] = (signed char)__float2int_rn(b.x * inv);
    q[5] = (signed char)__float2int_rn(b.y * inv);
    q[6] = (signed char)__float2int_rn(b.z * inv);
    q[7] = (signed char)__float2int_rn(b.w * inv);

    unsigned long long packed = 0;
    #pragma unroll
    for (int j = 0; j < 8; ++j)
        packed |= ((unsigned long long)(unsigned char)q[j]) << (8 * j);

    const int sl = lane >> 3;            // slice of dims 8L..8L+7
    *reinterpret_cast<unsigned long long*>(
        qtab + (size_t)sl * SLICE_BYTES + (size_t)row * 64 + (lane & 7) * 8) = packed;

    if (lane == 0) scales[row] = scale;
}

// ---------- phase 2: sliced gather ----------
__global__ __launch_bounds__(256) void sliced_gather_kernel(
    const int* __restrict__ inputs,       // [B*S]
    const signed char* __restrict__ qtab, // [8][VOCAB, 64]
    const float* __restrict__ scales,     // [VOCAB]
    float* __restrict__ out)              // [B*S, 512]
{
    const int t    = threadIdx.x;
    const int lane = t & 63;
    const int w    = t >> 6;             // wave 0..3
    const int g    = lane >> 4;          // group 0..3 within wave
    const int li   = lane & 15;          // dword index within slice
    const int sl   = blockIdx.x & 7;     // slice -> XCD (round-robin)
    const int wg   = blockIdx.x >> 3;    // 0..249 within slice
    const int base = wg * (NPOS / 250);  // 640 uses per block

    const int p0 = sl * 32 + 2 * li;
    const float f0 = exp2f((float)p0 * FREQ_C);
    const float f1 = exp2f((float)(p0 + 1) * FREQ_C);

    const signed char* __restrict__ qsl = qtab + (size_t)sl * SLICE_BYTES;
    const int out_off = sl * 64 + li * 4;   // float offset within 512-dim row

    #pragma unroll 4
    for (int i = 0; i < 40; ++i) {
        const int pos = base + i * 16 + w * 4 + g;     // ascending per block
        const unsigned int up = (unsigned int)pos;
        const int s = (int)(up % (unsigned int)EMB_S); // pos = b*S + s
        const int v = inputs[pos];
        const float sc = scales[v];
        const unsigned int u = *reinterpret_cast<const unsigned int*>(
            qsl + (size_t)v * 64 + li * 4);

        const float fs = (float)s;
        const float a0 = fs * f0, a1 = fs * f1;
        f32x4 r;
        r.x = fmaf((float)(int)(signed char)(u       ), sc, __sinf(a0));
        r.y = fmaf((float)(int)(signed char)(u >>  8 ), sc, __cosf(a0));
        r.z = fmaf((float)(int)(signed char)(u >> 16 ), sc, __sinf(a1));
        r.w = fmaf((float)(int)(signed char)(u >> 24 ), sc, __cosf(a1));

        // R11: regular store (the ONLY change vs R10)
        *reinterpret_cast<f32x4*>(out + (size_t)pos * EMB_D + out_off) = r;
    }
}

// ---------- fallback (fp32 forward) if ws too small ----------
__global__ __launch_bounds__(256) void forward_kernel(
    const int* __restrict__ inputs,
    const float* __restrict__ weight,
    float* __restrict__ out)
{
    const int tid = blockIdx.x * blockDim.x + threadIdx.x;
    const int dvec = tid & 127;
    const int s    = tid >> 7;
    if (s >= EMB_S) return;

    int tokens[EMB_B];
    #pragma unroll
    for (int b = 0; b < EMB_B; ++b) tokens[b] = inputs[b * EMB_S + s];

    const float f0 = exp2f((float)(4 * dvec)     * FREQ_C);
    const float f1 = exp2f((float)(4 * dvec + 2) * FREQ_C);
    const float a0 = (float)s * f0, a1 = (float)s * f1;
    f32x4 pe;
    pe.x = __sinf(a0); pe.y = __cosf(a0);
    pe.z = __sinf(a1); pe.w = __cosf(a1);

    const f32x4* __restrict__ w4 = reinterpret_cast<const f32x4*>(weight);
    f32x4* __restrict__ o4 = reinterpret_cast<f32x4*>(out);
    const int row_off = s * 128 + dvec;

    #pragma unroll 8
    for (int b = 0; b < EMB_B; ++b) {
        const f32x4 e = w4[(size_t)tokens[b] * 128 + dvec];
        o4[(size_t)b * (EMB_S * 128) + row_off] = e + pe;
    }
}

extern "C" void kernel_launch(void* const* d_in, const int* in_sizes, int n_in,
                              void* d_out, int out_size, void* d_ws, size_t ws_size,
                              hipStream_t stream) {
    const int*   inputs = (const int*)d_in[0];     // [32, 5000] int32
    const float* weight = (const float*)d_in[1];   // [32000, 512] fp32
    float*       out    = (float*)d_out;           // [32, 5000, 512] fp32

    const size_t qtab_bytes  = (size_t)NSLICE * SLICE_BYTES;     // 16.384 MB
    const size_t scale_bytes = (size_t)VOCAB * sizeof(float);    // 128 KB

    if (ws_size >= qtab_bytes + scale_bytes) {
        signed char* qtab = (signed char*)d_ws;
        float* scales = (float*)((char*)d_ws + qtab_bytes);

        quant_kernel<<<VOCAB / 4, 256, 0, stream>>>(weight, qtab, scales);

        sliced_gather_kernel<<<2000, 256, 0, stream>>>(
            inputs, qtab, scales, out);
    } else {
        const int total_threads = EMB_S * 128;
        forward_kernel<<<(total_threads + 255) / 256, 256, 0, stream>>>(
            inputs, weight, out);
    }
}

// Round 12
// 73.640 us; speedup vs baseline: 1.2779x; 1.2779x over previous
//
#include <hip/hip_runtime.h>
#include <hip/hip_bf16.h>

// ComputeEmbeddings: out[b,s,d] = embed_weight[inputs[b,s], d] + PE[s,d]
//   B=32, S=5000, D=512, VOCAB=32000, fp32. absmax threshold 0.128.
//
// R10 -> R12 (R11 A/B confirmed nt stores are load-bearing; they stay).
// One variable vs R10: slice width 64 -> 128 dims (4 slices, 2 XCDs per
// slice). Theory: gather is write-limited at 5.05 TB/s because nt stores
// emit 256B chunks at 2KB stride (1/8 density) which lose ~25% DRAM
// efficiency vs sequential. 128-dim slices double the chunk to 512B.
// Cost: slice = 4.10MB vs 4MiB L2 (slight overflow; nt writes don't
// pollute so only inputs+scales compete).
//   XCD pairing: xcd=blockIdx&7, sl=xcd>>1; xcd 2k handles pos[0,80000),
//   xcd 2k+1 handles pos[80000,160000) for slice k.

#define EMB_B  32
#define EMB_S  5000
#define EMB_D  512
#define VOCAB  32000
#define NPOS   (EMB_B * EMB_S)        // 160000
#define NSLICE 4
#define SLICE_BYTES ((size_t)VOCAB * 128)   // 4,096,000 B per slice

typedef float f32x4 __attribute__((ext_vector_type(4)));

#define LOG2_10000 13.287712379549449f
#define FREQ_C (-(LOG2_10000 / 256.0f))   // inv_freq(i) = exp2(i * FREQ_C)

// ---------- phase 1: per-row int8 quantization into SLICED layout ----------
// One wave per row. Lane L holds dims 8L..8L+7 -> slice L>>4, bytes
// (L&15)*8 within the row's 128B slice segment (16-lane groups contiguous).
__global__ __launch_bounds__(256) void quant_kernel(
    const float* __restrict__ weight,   // [VOCAB, 512]
    signed char* __restrict__ qtab,     // [4][VOCAB, 128]
    float* __restrict__ scales)         // [VOCAB]
{
    const int gtid = blockIdx.x * 256 + threadIdx.x;
    const int row  = gtid >> 6;          // one wave per row
    const int lane = gtid & 63;
    if (row >= VOCAB) return;

    const f32x4* __restrict__ w4 =
        reinterpret_cast<const f32x4*>(weight + (size_t)row * EMB_D);
    const f32x4 a = w4[lane * 2];
    const f32x4 b = w4[lane * 2 + 1];

    float m = fmaxf(fmaxf(fabsf(a.x), fabsf(a.y)), fmaxf(fabsf(a.z), fabsf(a.w)));
    m = fmaxf(m, fmaxf(fmaxf(fabsf(b.x), fabsf(b.y)), fmaxf(fabsf(b.z), fabsf(b.w))));
    #pragma unroll
    for (int off = 1; off < 64; off <<= 1)
        m = fmaxf(m, __shfl_xor(m, off));

    const float scale = m * (1.0f / 127.0f);
    const float inv   = (m > 0.0f) ? (127.0f / m) : 0.0f;

    signed char q[8];
    q[0] = (signed char)__float2int_rn(a.x * inv);
    q[1] = (signed char)__float2int_rn(a.y * inv);
    q[2] = (signed char)__float2int_rn(a.z * inv);
    q[3] = (signed char)__float2int_rn(a.w * inv);
    q[4] = (signed char)__float2int_rn(b.x * inv);
    q[5] = (signed char)__float2int_rn(b.y * inv);
    q[6] = (signed char)__float2int_rn(b.z * inv);
    q[7] = (signed char)__float2int_rn(b.w * inv);

    unsigned long long packed = 0;
    #pragma unroll
    for (int j = 0; j < 8; ++j)
        packed |= ((unsigned long long)(unsigned char)q[j]) << (8 * j);

    const int sl = lane >> 4;            // slice of dims 8L..8L+7
    *reinterpret_cast<unsigned long long*>(
        qtab + (size_t)sl * SLICE_BYTES + (size_t)row * 128 + (lane & 15) * 8) = packed;

    if (lane == 0) scales[row] = scale;
}

// ---------- phase 2: sliced gather ----------
// xcd = blockIdx&7 -> slice xcd>>1; half = xcd&1 selects position half.
// 32-lane group per use: li covers dims sl*128 + 4*li..+3 (4B qtab read,
// 16B nt store; 512B contiguous per use-slice).
__global__ __launch_bounds__(256) void sliced_gather_kernel(
    const int* __restrict__ inputs,       // [B*S]
    const signed char* __restrict__ qtab, // [4][VOCAB, 128]
    const float* __restrict__ scales,     // [VOCAB]
    float* __restrict__ out)              // [B*S, 512]
{
    const int t    = threadIdx.x;
    const int lane = t & 63;
    const int w    = t >> 6;             // wave 0..3
    const int g    = lane >> 5;          // group 0..1 within wave
    const int li   = lane & 31;          // dword index within slice
    const int xcd  = blockIdx.x & 7;     // XCD (round-robin)
    const int sl   = xcd >> 1;           // slice (2 XCDs per slice)
    const int wg   = blockIdx.x >> 3;    // 0..249
    // xcd 2k: positions [0, 80000); xcd 2k+1: [80000, 160000). 320/block.
    const int base = (xcd & 1) * (NPOS / 2) + wg * 320;

    // Thread-constant PE frequencies: dims d = sl*128 + 4*li + {0..3}
    // -> pair indices p0 = sl*64 + 2*li, p1 = p0+1.
    const int p0 = sl * 64 + 2 * li;
    const float f0 = exp2f((float)p0 * FREQ_C);
    const float f1 = exp2f((float)(p0 + 1) * FREQ_C);

    const signed char* __restrict__ qsl = qtab + (size_t)sl * SLICE_BYTES;
    const int out_off = sl * 128 + li * 4;  // float offset within 512-dim row

    #pragma unroll 4
    for (int i = 0; i < 40; ++i) {
        const int pos = base + i * 8 + w * 2 + g;      // ascending per block
        const unsigned int up = (unsigned int)pos;
        const int s = (int)(up % (unsigned int)EMB_S); // pos = b*S + s
        const int v = inputs[pos];
        const float sc = scales[v];
        const unsigned int u = *reinterpret_cast<const unsigned int*>(
            qsl + (size_t)v * 128 + li * 4);

        const float fs = (float)s;
        const float a0 = fs * f0, a1 = fs * f1;
        f32x4 r;
        r.x = fmaf((float)(int)(signed char)(u       ), sc, __sinf(a0));
        r.y = fmaf((float)(int)(signed char)(u >>  8 ), sc, __cosf(a0));
        r.z = fmaf((float)(int)(signed char)(u >> 16 ), sc, __sinf(a1));
        r.w = fmaf((float)(int)(signed char)(u >> 24 ), sc, __cosf(a1));

        __builtin_nontemporal_store(
            r, reinterpret_cast<f32x4*>(out + (size_t)pos * EMB_D + out_off));
    }
}

// ---------- fallback (fp32 forward) if ws too small ----------
__global__ __launch_bounds__(256) void forward_kernel(
    const int* __restrict__ inputs,
    const float* __restrict__ weight,
    float* __restrict__ out)
{
    const int tid = blockIdx.x * blockDim.x + threadIdx.x;
    const int dvec = tid & 127;
    const int s    = tid >> 7;
    if (s >= EMB_S) return;

    int tokens[EMB_B];
    #pragma unroll
    for (int b = 0; b < EMB_B; ++b) tokens[b] = inputs[b * EMB_S + s];

    const float f0 = exp2f((float)(4 * dvec)     * FREQ_C);
    const float f1 = exp2f((float)(4 * dvec + 2) * FREQ_C);
    const float a0 = (float)s * f0, a1 = (float)s * f1;
    f32x4 pe;
    pe.x = __sinf(a0); pe.y = __cosf(a0);
    pe.z = __sinf(a1); pe.w = __cosf(a1);

    const f32x4* __restrict__ w4 = reinterpret_cast<const f32x4*>(weight);
    f32x4* __restrict__ o4 = reinterpret_cast<f32x4*>(out);
    const int row_off = s * 128 + dvec;

    #pragma unroll 8
    for (int b = 0; b < EMB_B; ++b) {
        const f32x4 e = w4[(size_t)tokens[b] * 128 + dvec];
        o4[(size_t)b * (EMB_S * 128) + row_off] = e + pe;
    }
}

extern "C" void kernel_launch(void* const* d_in, const int* in_sizes, int n_in,
                              void* d_out, int out_size, void* d_ws, size_t ws_size,
                              hipStream_t stream) {
    const int*   inputs = (const int*)d_in[0];     // [32, 5000] int32
    const float* weight = (const float*)d_in[1];   // [32000, 512] fp32
    float*       out    = (float*)d_out;           // [32, 5000, 512] fp32

    const size_t qtab_bytes  = (size_t)NSLICE * SLICE_BYTES;     // 16.384 MB
    const size_t scale_bytes = (size_t)VOCAB * sizeof(float);    // 128 KB

    if (ws_size >= qtab_bytes + scale_bytes) {
        signed char* qtab = (signed char*)d_ws;
        float* scales = (float*)((char*)d_ws + qtab_bytes);

        quant_kernel<<<VOCAB / 4, 256, 0, stream>>>(weight, qtab, scales);

        // 250 blocks x 8 XCD-lanes = 2000 blocks; blockIdx%8 stays balanced.
        sliced_gather_kernel<<<2000, 256, 0, stream>>>(
            inputs, qtab, scales, out);
    } else {
        const int total_threads = EMB_S * 128;
        forward_kernel<<<(total_threads + 255) / 256, 256, 0, stream>>>(
            inputs, weight, out);
    }
}